// Round 2
// baseline (571.342 us; speedup 1.0000x reference)
//
#include <hip/hip_runtime.h>
#include <stdint.h>

// Problem constants
#define NN   16
#define HH   112
#define WW   112
#define CIN  256
#define COUT 256
#define HP   114          // padded height
#define WP   114          // padded width
#define M_TOTAL (NN * HH * WW)                    // 200704
#define XP_BYTES ((size_t)NN * HP * WP * CIN)     // 53,231,616
#define WPK_BYTES ((size_t)9 * COUT * CIN)        // 589,824

typedef int v4i __attribute__((ext_vector_type(4)));

__device__ __forceinline__ void load_lds16(const void* g, void* l) {
  __builtin_amdgcn_global_load_lds(
      (const __attribute__((address_space(1))) void*)g,
      (__attribute__((address_space(3))) void*)l, 16, 0, 0);
}

__device__ __forceinline__ void bar() {
  asm volatile("" ::: "memory");
  __builtin_amdgcn_s_barrier();
  asm volatile("" ::: "memory");
}

// register-only byte pack: 4 ints (int8-valued) -> one dword
__device__ __forceinline__ int pack4(int a, int b, int c, int d) {
  return (a & 255) | ((b & 255) << 8) | ((c & 255) << 16) | (d << 24);
}

// ---------------- pack x: int32 NHWC -> int8 padded [N][114][114][256] ----------------
__global__ void pack_x_kernel(const int* __restrict__ x, char* __restrict__ xp) {
  int t = blockIdx.x * 256 + threadIdx.x;   // exactly M_TOTAL*16 threads
  int g = t & 15;                           // 16B-group within pixel (16 ci each)
  int p = t >> 4;                           // pixel index
  int w = p % WW;
  int t2 = p / WW;
  int h = t2 % HH;
  int n = t2 / HH;
  const int4* src = (const int4*)(x + (size_t)t * 16);
  int4 a = src[0], b = src[1], c = src[2], d = src[3];
  int4 ov;
  ov.x = pack4(a.x, a.y, a.z, a.w);
  ov.y = pack4(b.x, b.y, b.z, b.w);
  ov.z = pack4(c.x, c.y, c.z, c.w);
  ov.w = pack4(d.x, d.y, d.z, d.w);
  size_t dst = (((size_t)n * HP + (h + 1)) * WP + (w + 1)) * CIN + (size_t)g * 16;
  *(int4*)(xp + dst) = ov;
}

// ---------------- fused: pack weight (blocks 0..575) + zero border (blocks 576..1027) ----
__global__ void pack_w_border_kernel(const int* __restrict__ wgt, char* __restrict__ xp,
                                     char* __restrict__ wp) {
  int bid = blockIdx.x;
  if (bid < 576) {
    int t = bid * 256 + threadIdx.x;        // exactly 2304*64 threads
    int c4 = t & 63;
    int r = t >> 6;                         // 0..2303 = cout*9 + tap
    int tap = r % 9;
    int cout = r / 9;
    int4 v = *(const int4*)(wgt + (size_t)t * 4);
    int ov = pack4(v.x, v.y, v.z, v.w);
    size_t dst = ((size_t)tap * COUT + cout) * CIN + (size_t)c4 * 4;
    *(int*)(wp + dst) = ov;
  } else {
    int t = (bid - 576) * 256 + threadIdx.x;  // exactly 452*256 threads
    int g = t & 15;
    int pix = t >> 4;                          // 0..7231
    int n = pix / 452;
    int b = pix % 452;
    int h, w;
    if (b < 114) { h = 0; w = b; }
    else if (b < 228) { h = 113; w = b - 114; }
    else { int r = b - 228; h = 1 + (r >> 1); w = (r & 1) ? 113 : 0; }
    size_t dst = (((size_t)n * HP + h) * WP + w) * CIN + (size_t)g * 16;
    *(int4*)(xp + dst) = make_int4(0, 0, 0, 0);
  }
}

// ---------------- implicit-GEMM conv: C[M=200704][256] = A[M][2304] * B[2304][256] ----------------
// A operand: DIRECT global->VGPR gathers (per-wave-exclusive rows; no LDS).
// B operand: LDS, triple-buffered, staged 2 steps ahead via global_load_lds.
// Per K-step per wave: 8 ds_read_b128 (B) + 4 global gathers (A, next step) +
// 4 global_load_lds (B, step+2) + 32 MFMA, ONE barrier.
// vmcnt discipline: per-step issue order [B-stage, A-gather]; before the MFMA
// cluster of step ks, vmcnt(8) retires exactly {B(ks+1), A(ks)} and leaves
// {B(ks+2), A(ks+1)} in flight across the barrier. Tail: 8,8,8,8,4,0.
__global__ __launch_bounds__(256, 2) void conv_mfma_kernel(const char* __restrict__ xp,
                                                           const char* __restrict__ wp,
                                                           int* __restrict__ out) {
  __shared__ __align__(16) char Bs[3 * 256 * 64];   // 48 KB (triple buffer, B only)
  const int tid = threadIdx.x;
  const int lane = tid & 63;
  const int wave = tid >> 6;
  const int mtile = blockIdx.x;
  const int wm = wave & 1;   // m half (64 rows)
  const int wn = wave >> 1;  // n half (128 cols)

  // ---- B staging: 16 chunks of 1 KB per step; each wave stages 4 ----
  // LDS layout per tile: row-major [256 rows][4 cols of 16B], XOR-swizzled:
  // position (row, c) holds global 16B-column (c ^ ((row>>1)&3)).
  const char* gptrB[4];
  char* lptrB[4];
#pragma unroll
  for (int j = 0; j < 4; j++) {
    int c = wave * 4 + j;                 // chunk 0..15
    int row = c * 16 + (lane >> 2);       // B row = cout 0..255
    int colg = (lane & 3) ^ ((row >> 1) & 3);
    gptrB[j] = wp + (size_t)row * CIN + (size_t)colg * 16;
    lptrB[j] = Bs + c * 1024;
  }

  // ---- A gather bases: 4 rows per lane-group; k-slice (lane>>4)*16 folded in ----
  const char* abase[4];
#pragma unroll
  for (int i = 0; i < 4; i++) {
    int ra = mtile * 128 + wm * 64 + i * 16 + (lane & 15);
    int w = ra % WW;
    int t2 = ra / WW;
    int h = t2 % HH;
    int n = t2 / HH;
    abase[i] = xp + (((size_t)n * HP + h) * WP + w) * CIN + (size_t)(lane >> 4) * 16;
  }

  // ---- B fragment LDS offsets (within one 16KB buffer) ----
  int boff[8];
#pragma unroll
  for (int j = 0; j < 8; j++) {
    int rb = wn * 128 + j * 16 + (lane & 15);
    boff[j] = rb * 64 + (((lane >> 4) ^ ((rb >> 1) & 3)) * 16);
  }

  v4i acc[4][8];
#pragma unroll
  for (int i = 0; i < 4; i++)
#pragma unroll
    for (int j = 0; j < 8; j++) acc[i][j] = (v4i){0, 0, 0, 0};

  auto stageB = [&](int ks, int b) {
    int tap = ks >> 2;
    int kb = ks & 3;
    int offB = tap * (COUT * CIN) + kb * 64;
#pragma unroll
    for (int j = 0; j < 4; j++) load_lds16(gptrB[j] + offB, lptrB[j] + b * 16384);
  };
  auto gatherA = [&](int ks, v4i* dst) {
    int tap = ks >> 2;
    int kb = ks & 3;
    int ky = tap / 3;
    int kx = tap - ky * 3;
    int off = (ky * WP + kx) * CIN + kb * 64;
#pragma unroll
    for (int i = 0; i < 4; i++) dst[i] = *(const v4i*)(abase[i] + off);
  };

  v4i afr[2][4];   // A ping-pong (statically indexed via unroll)

  // prologue: B(0)->buf0, B(1)->buf1 staged; A(0)->slot0 gathered.
  // queue: [B0(4), B1(4), A0(4)]; vmcnt(8) retires B0 (B1, A0 stay in flight).
  stageB(0, 0);
  stageB(1, 1);
  gatherA(0, afr[0]);
  asm volatile("s_waitcnt vmcnt(8)" ::: "memory");
  bar();

#define CONV_STEP(KS, BC, CUR, NXT, DOSTAGE, DOGATHER, VMN)                         \
  {                                                                                 \
    const char* Bb = Bs + (BC) * 16384;                                             \
    v4i bf[8];                                                                      \
    _Pragma("unroll") for (int j = 0; j < 8; j++)                                   \
        bf[j] = *(const v4i*)(Bb + boff[j]);                                        \
    if (DOSTAGE) stageB((KS) + 2, ((BC) + 2) % 3);                                  \
    if (DOGATHER) gatherA((KS) + 1, afr[NXT]);                                      \
    asm volatile("s_waitcnt vmcnt(" VMN ")" ::: "memory");                          \
    __builtin_amdgcn_s_setprio(1);                                                  \
    _Pragma("unroll") for (int i = 0; i < 4; i++)                                   \
      _Pragma("unroll") for (int j = 0; j < 8; j++)                                 \
        acc[i][j] = __builtin_amdgcn_mfma_i32_16x16x64_i8(afr[CUR][i], bf[j],       \
                                                          acc[i][j], 0, 0, 0);      \
    __builtin_amdgcn_s_setprio(0);                                                  \
    bar();                                                                          \
  }

  // main loop: ks = 0..29 (stage ks+2 <= 31, gather ks+1 <= 30 always valid)
#pragma unroll 1
  for (int it = 0; it < 5; it++) {
    int base = it * 6;
#pragma unroll
    for (int u = 0; u < 6; u++) {
      CONV_STEP(base + u, u % 3, u & 1, (u + 1) & 1, true, true, "8")
    }
  }
  // peeled tail: ks = 30..35
  CONV_STEP(30, 0, 0, 1, true,  true,  "8")
  CONV_STEP(31, 1, 1, 0, true,  true,  "8")
  CONV_STEP(32, 2, 0, 1, true,  true,  "8")
  CONV_STEP(33, 0, 1, 0, true,  true,  "8")
  CONV_STEP(34, 1, 0, 1, false, true,  "4")
  CONV_STEP(35, 2, 1, 0, false, false, "0")
#undef CONV_STEP

  // ---- epilogue: C/D layout col=lane&15, row=(lane>>4)*4+reg ----
#pragma unroll
  for (int i = 0; i < 4; i++) {
    const int mg = mtile * 128 + wm * 64 + i * 16 + ((lane >> 4) * 4);
#pragma unroll
    for (int r = 0; r < 4; r++) {
      int* orow = out + (size_t)(mg + r) * COUT + wn * 128 + (lane & 15);
#pragma unroll
      for (int j = 0; j < 8; j++) orow[j * 16] = acc[i][j][r];
    }
  }
}

// ---------------- fallback (only if ws too small): direct int32 conv ----------------
__global__ void conv_naive_kernel(const int* __restrict__ x, const int* __restrict__ wgt,
                                  int* __restrict__ out, int total) {
  int idx = blockIdx.x * 256 + threadIdx.x;
  if (idx >= total) return;
  int co = idx & 255;
  int p = idx >> 8;
  int w = p % WW;
  int t2 = p / WW;
  int h = t2 % HH;
  int n = t2 / HH;
  int acc = 0;
  for (int ky = 0; ky < 3; ky++) {
    int ih = h + ky - 1;
    if (ih < 0 || ih >= HH) continue;
    for (int kx = 0; kx < 3; kx++) {
      int iw = w + kx - 1;
      if (iw < 0 || iw >= WW) continue;
      const int* xs = x + (((size_t)n * HH + ih) * WW + iw) * CIN;
      const int* ws = wgt + ((size_t)co * 9 + ky * 3 + kx) * CIN;
      for (int ci = 0; ci < CIN; ci++) acc += xs[ci] * ws[ci];
    }
  }
  out[idx] = acc;
}

extern "C" void kernel_launch(void* const* d_in, const int* in_sizes, int n_in,
                              void* d_out, int out_size, void* d_ws, size_t ws_size,
                              hipStream_t stream) {
  const int* x = (const int*)d_in[0];
  const int* wgt = (const int*)d_in[1];
  int* out = (int*)d_out;
  const size_t need = XP_BYTES + WPK_BYTES;
  if (ws_size >= need) {
    char* xp = (char*)d_ws;
    char* wp = xp + XP_BYTES;
    pack_x_kernel<<<(M_TOTAL * 16) / 256, 256, 0, stream>>>(x, xp);       // 12544 blocks
    pack_w_border_kernel<<<576 + 452, 256, 0, stream>>>(wgt, xp, wp);     // 1028 blocks
    conv_mfma_kernel<<<M_TOTAL / 128, 256, 0, stream>>>(xp, wp, out);     // 1568 blocks
  } else {
    conv_naive_kernel<<<(out_size + 255) / 256, 256, 0, stream>>>(x, wgt, out, out_size);
  }
}

// Round 3
// 473.135 us; speedup vs baseline: 1.2076x; 1.2076x over previous
//
#include <hip/hip_runtime.h>
#include <stdint.h>

// Problem constants
#define NN   16
#define HH   112
#define WW   112
#define CIN  256
#define COUT 256
#define HP   114          // padded height
#define WP   114          // padded width
#define M_TOTAL (NN * HH * WW)                    // 200704
#define XP_BYTES ((size_t)NN * HP * WP * CIN)     // 53,231,616
#define WPK_BYTES ((size_t)9 * COUT * CIN)        // 589,824

typedef int v4i __attribute__((ext_vector_type(4)));

__device__ __forceinline__ void load_lds16(const void* g, void* l) {
  __builtin_amdgcn_global_load_lds(
      (const __attribute__((address_space(1))) void*)g,
      (__attribute__((address_space(3))) void*)l, 16, 0, 0);
}

// register-only byte pack: 4 ints (int8-valued) -> one dword
__device__ __forceinline__ int pack4(int a, int b, int c, int d) {
  return (a & 255) | ((b & 255) << 8) | ((c & 255) << 16) | (d << 24);
}

// ---------------- fused pack: x (blocks 0..12543), weight (12544..13119), border (13120..13571)
__global__ __launch_bounds__(256) void pack_all_kernel(const int* __restrict__ x,
                                                       const int* __restrict__ wgt,
                                                       char* __restrict__ xp,
                                                       char* __restrict__ wp) {
  int bid = blockIdx.x;
  if (bid < 12544) {
    // pack x: one thread per 16 ints -> one 16B packed store
    int t = bid * 256 + threadIdx.x;          // M_TOTAL*16 threads
    int g = t & 15;
    int p = t >> 4;
    int w = p % WW;
    int t2 = p / WW;
    int h = t2 % HH;
    int n = t2 / HH;
    const int4* src = (const int4*)(x + (size_t)t * 16);
    int4 a = src[0], b = src[1], c = src[2], d = src[3];
    int4 ov;
    ov.x = pack4(a.x, a.y, a.z, a.w);
    ov.y = pack4(b.x, b.y, b.z, b.w);
    ov.z = pack4(c.x, c.y, c.z, c.w);
    ov.w = pack4(d.x, d.y, d.z, d.w);
    size_t dst = (((size_t)n * HP + (h + 1)) * WP + (w + 1)) * CIN + (size_t)g * 16;
    *(int4*)(xp + dst) = ov;
  } else if (bid < 12544 + 576) {
    // pack weight: OHWI int32 -> int8 [tap][cout][cin]
    int t = (bid - 12544) * 256 + threadIdx.x;   // 2304*64 threads
    int c4 = t & 63;
    int r = t >> 6;                              // cout*9 + tap
    int tap = r % 9;
    int cout = r / 9;
    int4 v = *(const int4*)(wgt + (size_t)t * 4);
    int ov = pack4(v.x, v.y, v.z, v.w);
    size_t dst = ((size_t)tap * COUT + cout) * CIN + (size_t)c4 * 4;
    *(int*)(wp + dst) = ov;
  } else {
    // zero the 1-pixel border of xp
    int t = (bid - 13120) * 256 + threadIdx.x;   // 452*256 threads
    int g = t & 15;
    int pix = t >> 4;                            // 0..7231
    int n = pix / 452;
    int b = pix % 452;
    int h, w;
    if (b < 114) { h = 0; w = b; }
    else if (b < 228) { h = 113; w = b - 114; }
    else { int r = b - 228; h = 1 + (r >> 1); w = (r & 1) ? 113 : 0; }
    size_t dst = (((size_t)n * HP + h) * WP + w) * CIN + (size_t)g * 16;
    *(int4*)(xp + dst) = make_int4(0, 0, 0, 0);
  }
}

// ---------------- implicit-GEMM conv, 8-phase-template structure ----------------
// C[M=200704][256] = A[M][2304] * B[2304][256]
// Tile 256x256, 512 threads / 8 waves (2M x 4N); per wave 128m x 64n
// = 8x4 MFMA 16x16x64 tiles, 32 MFMA per K-step (BK=64 i8).
// LDS: A and B each 4 buffers x 256 rows x 64 B (swizzled) = 128 KiB total.
// Staging: 3 K-steps ahead (lead ~960cy > HBM latency); 4 load_lds16/thread/step.
// Per step: 2 phases {ds_read ; stage ; barrier ; lgkmcnt(0) ; setprio(1) ;
// 16 MFMA ; setprio(0) ; barrier}; ONE counted vmcnt(8) per step before the
// final barrier (retires exactly the stage for the NEXT step; 8 stay in flight).
// Tail: vmcnt 8,4,0.
__global__ __launch_bounds__(512, 2) void conv_mfma_kernel(const char* __restrict__ xp,
                                                           const char* __restrict__ wp,
                                                           int* __restrict__ out) {
  __shared__ __align__(16) char As[4 * 16384];   // 64 KB
  __shared__ __align__(16) char Bs[4 * 16384];   // 64 KB
  const int tid = threadIdx.x;
  const int lane = tid & 63;
  const int wave = tid >> 6;   // 0..7
  const int mtile = blockIdx.x;
  const int wm = wave & 1;     // m half (128 rows)
  const int wn = wave >> 1;    // n quarter (64 cols)

  // ---- staging sources (per thread). LDS tile layout: [256 rows][4 x 16B cols],
  // position (row,c) holds global 16B-column (c ^ ((row>>1)&3)).
  // Thread t covers LDS linear pos t*16 of each 8KB half-tile (rows j*128 + t>>2).
  const int rA0 = (tid >> 2);
  const int rA1 = 128 + (tid >> 2);
  const int gcA0 = (tid & 3) ^ ((rA0 >> 1) & 3);
  const int gcA1 = (tid & 3) ^ ((rA1 >> 1) & 3);
  const char *gsrcA0, *gsrcA1;
  {
    int m0 = mtile * 256 + rA0;
    int w0 = m0 % WW; int q0 = m0 / WW; int h0 = q0 % HH; int n0 = q0 / HH;
    gsrcA0 = xp + (((size_t)n0 * HP + h0) * WP + w0) * CIN + (size_t)gcA0 * 16;
    int m1 = mtile * 256 + rA1;
    int w1 = m1 % WW; int q1 = m1 / WW; int h1 = q1 % HH; int n1 = q1 / HH;
    gsrcA1 = xp + (((size_t)n1 * HP + h1) * WP + w1) * CIN + (size_t)gcA1 * 16;
  }
  const char* gsrcB0 = wp + (size_t)rA0 * CIN + (size_t)gcA0 * 16;   // B rows = cout
  const char* gsrcB1 = wp + (size_t)rA1 * CIN + (size_t)gcA1 * 16;

  // ---- read-side fragment LDS offsets (within one 16KB buffer) ----
  int aoff[8], boff[4];
#pragma unroll
  for (int i = 0; i < 8; i++) {
    int r = wm * 128 + i * 16 + (lane & 15);
    aoff[i] = r * 64 + (((lane >> 4) ^ ((r >> 1) & 3)) * 16);
  }
#pragma unroll
  for (int j = 0; j < 4; j++) {
    int rb = wn * 64 + j * 16 + (lane & 15);
    boff[j] = rb * 64 + (((lane >> 4) ^ ((rb >> 1) & 3)) * 16);
  }

  v4i acc[8][4];
#pragma unroll
  for (int i = 0; i < 8; i++)
#pragma unroll
    for (int j = 0; j < 4; j++) acc[i][j] = (v4i){0, 0, 0, 0};

  // stage K-step data at global offsets (oA,oB) into buffer buf
  auto stage = [&](int oA, int oB, int buf) {
    char* Adst = As + buf * 16384 + wave * 1024;
    char* Bdst = Bs + buf * 16384 + wave * 1024;
    load_lds16(gsrcA0 + oA, Adst);
    load_lds16(gsrcA1 + oA, Adst + 8192);
    load_lds16(gsrcB0 + oB, Bdst);
    load_lds16(gsrcB1 + oB, Bdst + 8192);
  };

  // prologue: steps 0,1,2 (all tap 0: offA base 0) into bufs 0,1,2
  stage(0, 0, 0);
  stage(64, 64, 1);
  stage(128, 128, 2);
  asm volatile("s_waitcnt vmcnt(8)" ::: "memory");   // step 0's 4 loads landed
  __builtin_amdgcn_s_barrier();

// one K-step: buffer U (=ks%4), stage (SOA,SOB) for step ks+3 into buf (U+3)&3
#define CONV_STEP(U, SOA, SOB, DOSTAGE, VMN)                                        \
  {                                                                                 \
    const char* Ab = As + (U) * 16384;                                              \
    const char* Bb = Bs + (U) * 16384;                                              \
    v4i af[4], bf[4], af2[4];                                                       \
    /* phase 1: frags m0..3 + all B; stage; 16 MFMA */                              \
    _Pragma("unroll") for (int i = 0; i < 4; i++)                                   \
        af[i] = *(const v4i*)(Ab + aoff[i]);                                        \
    _Pragma("unroll") for (int j = 0; j < 4; j++)                                   \
        bf[j] = *(const v4i*)(Bb + boff[j]);                                        \
    if (DOSTAGE) stage((SOA), (SOB), ((U) + 3) & 3);                                \
    __builtin_amdgcn_s_barrier();                                                   \
    asm volatile("s_waitcnt lgkmcnt(0)" ::: "memory");                              \
    __builtin_amdgcn_s_setprio(1);                                                  \
    _Pragma("unroll") for (int i = 0; i < 4; i++)                                   \
      _Pragma("unroll") for (int j = 0; j < 4; j++)                                 \
        acc[i][j] = __builtin_amdgcn_mfma_i32_16x16x64_i8(af[i], bf[j],             \
                                                          acc[i][j], 0, 0, 0);      \
    __builtin_amdgcn_s_setprio(0);                                                  \
    __builtin_amdgcn_s_barrier();                                                   \
    /* phase 2: frags m4..7, reuse bf; 16 MFMA; counted vmcnt; barrier */           \
    _Pragma("unroll") for (int i = 0; i < 4; i++)                                   \
        af2[i] = *(const v4i*)(Ab + aoff[4 + i]);                                   \
    __builtin_amdgcn_s_barrier();                                                   \
    asm volatile("s_waitcnt lgkmcnt(0)" ::: "memory");                              \
    __builtin_amdgcn_s_setprio(1);                                                  \
    _Pragma("unroll") for (int i = 0; i < 4; i++)                                   \
      _Pragma("unroll") for (int j = 0; j < 4; j++)                                 \
        acc[4 + i][j] = __builtin_amdgcn_mfma_i32_16x16x64_i8(af2[i], bf[j],        \
                                                              acc[4 + i][j], 0, 0, 0); \
    __builtin_amdgcn_s_setprio(0);                                                  \
    asm volatile("s_waitcnt vmcnt(" VMN ")" ::: "memory");                          \
    __builtin_amdgcn_s_barrier();                                                   \
  }

  // main loop: groups g=0..7 cover steps 0..31 (stage targets <= step 34)
#pragma unroll 1
  for (int g = 0; g < 8; g++) {
    // stage offsets: u=0 stages step 4g+3 (tap g, kb 3); u=1..3 stage tap g+1, kb 0..2
    int ky0 = g / 3, kx0 = g - ky0 * 3;
    int oA0 = (ky0 * WP + kx0) * CIN;
    int oB0 = g * (COUT * CIN);
    int ky1 = (g + 1) / 3, kx1 = (g + 1) - ky1 * 3;
    int oA1 = (ky1 * WP + kx1) * CIN;
    int oB1 = (g + 1) * (COUT * CIN);
    CONV_STEP(0, oA0 + 192, oB0 + 192, true, "8")
    CONV_STEP(1, oA1,       oB1,       true, "8")
    CONV_STEP(2, oA1 + 64,  oB1 + 64,  true, "8")
    CONV_STEP(3, oA1 + 128, oB1 + 128, true, "8")
  }
  // peeled tail group: steps 32..35 (tap 8); step 32 stages step 35 (tap 8, kb 3)
  {
    int oA8 = (2 * WP + 2) * CIN;
    int oB8 = 8 * (COUT * CIN);
    CONV_STEP(0, oA8 + 192, oB8 + 192, true,  "8")
    CONV_STEP(1, 0, 0, false, "4")
    CONV_STEP(2, 0, 0, false, "0")
    CONV_STEP(3, 0, 0, false, "0")
  }
#undef CONV_STEP

  // ---- epilogue: C/D layout col=lane&15, row=(lane>>4)*4+reg ----
#pragma unroll
  for (int i = 0; i < 8; i++) {
    const int mg = mtile * 256 + wm * 128 + i * 16 + ((lane >> 4) * 4);
#pragma unroll
    for (int r = 0; r < 4; r++) {
      int* orow = out + (size_t)(mg + r) * COUT + wn * 64 + (lane & 15);
#pragma unroll
      for (int j = 0; j < 4; j++) orow[j * 16] = acc[i][j][r];
    }
  }
}

// ---------------- fallback (only if ws too small): direct int32 conv ----------------
__global__ void conv_naive_kernel(const int* __restrict__ x, const int* __restrict__ wgt,
                                  int* __restrict__ out, int total) {
  int idx = blockIdx.x * 256 + threadIdx.x;
  if (idx >= total) return;
  int co = idx & 255;
  int p = idx >> 8;
  int w = p % WW;
  int t2 = p / WW;
  int h = t2 % HH;
  int n = t2 / HH;
  int acc = 0;
  for (int ky = 0; ky < 3; ky++) {
    int ih = h + ky - 1;
    if (ih < 0 || ih >= HH) continue;
    for (int kx = 0; kx < 3; kx++) {
      int iw = w + kx - 1;
      if (iw < 0 || iw >= WW) continue;
      const int* xs = x + (((size_t)n * HH + ih) * WW + iw) * CIN;
      const int* ws = wgt + ((size_t)co * 9 + ky * 3 + kx) * CIN;
      for (int ci = 0; ci < CIN; ci++) acc += xs[ci] * ws[ci];
    }
  }
  out[idx] = acc;
}

extern "C" void kernel_launch(void* const* d_in, const int* in_sizes, int n_in,
                              void* d_out, int out_size, void* d_ws, size_t ws_size,
                              hipStream_t stream) {
  const int* x = (const int*)d_in[0];
  const int* wgt = (const int*)d_in[1];
  int* out = (int*)d_out;
  const size_t need = XP_BYTES + WPK_BYTES;
  if (ws_size >= need) {
    char* xp = (char*)d_ws;
    char* wp = xp + XP_BYTES;
    pack_all_kernel<<<13572, 256, 0, stream>>>(x, wgt, xp, wp);
    conv_mfma_kernel<<<M_TOTAL / 256, 512, 0, stream>>>(xp, wp, out);   // 784 blocks
  } else {
    conv_naive_kernel<<<(out_size + 255) / 256, 256, 0, stream>>>(x, wgt, out, out_size);
  }
}